// Round 5
// baseline (198.584 us; speedup 1.0000x reference)
//
#include <hip/hip_runtime.h>
#include <hip/hip_bf16.h>

// CompanyOperationEvaluation R14: B operands direct global->VGPR (no b_sh).
//  Theory: R13 refuted L2-congestion; LDS pipe (80 ds-instr/step ~1280cyc)
//  + 8-wave barrier sync per step is the serializer. Fix: per-wave B
//  fragments loaded straight from L2-resident weight arrays into a 3-deep
//  register ring (lookahead ~3 steps). Removes ds_write staging, removes
//  ALL intra-phase barriers (A_sh read-only within a phase) -> 7 barriers
//  total. LDS/step drops 80->32 instr. x1_sh becomes its own buffer.
//  Shape kept from R13: 256 blocks x 64 rows x 512 threads (8 waves 2x4),
//  LDS 108.5KB -> 1 block/CU, VGPR cap 256 (no pressure risk).
// Lesson bank: (R2) revisited DELIBERATELY: failure was unprefetched global
// MFMA operands; ring prefetch + reg deps give counted-vmcnt slack. If this
// regresses, R2 generalizes and we revert to R12. (R5) 8 MFMAs/wave/step
// kept; (R6) gather issued at top, consumed post-L1; (R13) weight-request
// rate is NOT the bottleneck.

typedef __bf16 bf16x8 __attribute__((ext_vector_type(8)));
typedef float floatx4 __attribute__((ext_vector_type(4)));

__device__ __forceinline__ unsigned short f2bf(float x) {
  unsigned int u = __builtin_bit_cast(unsigned int, x);
  u = (u + 0x7FFFu + ((u >> 16) & 1u)) >> 16;
  return (unsigned short)u;
}

#define PHASE_BAR()                                      \
  do {                                                   \
    asm volatile("s_waitcnt lgkmcnt(0)" ::: "memory");   \
    __builtin_amdgcn_s_barrier();                        \
    __builtin_amdgcn_sched_barrier(0);                   \
  } while (0)

// ---------------------------------------------------------------------------
// K1 prep: blocks [0,304) 32x32 transpose tiles; block 304 W2.
// ---------------------------------------------------------------------------
__global__ __launch_bounds__(256) void prep_kernel(
    const float* __restrict__ Wf, const float* __restrict__ Wu,
    const float* __restrict__ W0, const float* __restrict__ W1,
    const float* __restrict__ W2,
    unsigned short* __restrict__ wfT, unsigned short* __restrict__ wuT,
    unsigned short* __restrict__ w0T, unsigned short* __restrict__ w1T,
    unsigned short* __restrict__ w2T) {
  __shared__ unsigned short tile[32][34];
  const int bid = blockIdx.x, tid = threadIdx.x;
  if (bid < 304) {
    int t = bid;
    const float* src; unsigned short* dst; int N, K, kt, nt;
    if (t < 32)       { src = Wf; dst = wfT; N = 128; K = 256; kt = t >> 2;       nt = t & 3; }
    else if (t < 48)  { t -= 32;  src = Wu; dst = wuT; N = 128; K = 128; kt = t >> 2; nt = t & 3; }
    else if (t < 176) { t -= 48;  src = W0; dst = w0T; N = 512; K = 256; kt = t >> 4; nt = t & 15; }
    else              { t -= 176; src = W1; dst = w1T; N = 256; K = 512; kt = t >> 3; nt = t & 7; }
    {
      int r = tid >> 3, cg = (tid & 7) * 4;
      float4 v = *(const float4*)(src + (size_t)(kt * 32 + r) * N + nt * 32 + cg);
      tile[r][cg + 0] = f2bf(v.x); tile[r][cg + 1] = f2bf(v.y);
      tile[r][cg + 2] = f2bf(v.z); tile[r][cg + 3] = f2bf(v.w);
    }
    __syncthreads();
    {
      int rp = tid >> 3, cg = (tid & 7) * 4;
      uint2 o;
      o.x = (unsigned)tile[cg + 0][rp] | ((unsigned)tile[cg + 1][rp] << 16);
      o.y = (unsigned)tile[cg + 2][rp] | ((unsigned)tile[cg + 3][rp] << 16);
      *(uint2*)(dst + (size_t)(nt * 32 + rp) * K + kt * 32 + cg) = o;
    }
  } else {
#pragma unroll
    for (int i = 0; i < 8; ++i) {
      int g = tid * 8 + i, k = g >> 3, n = g & 7;
      w2T[n * 256 + k] = f2bf(W2[g]);
    }
  }
}

// ---------------------------------------------------------------------------
// Reg-direct phase helpers. B fragments: wave (wn) reads rows
// np*128 + wn*32 + {m16, 16+m16}, cols k0 + kk + quad*8 -- 16 rows x 64B
// contiguous segments per load instruction (coalesced, 128B/row/step).
// ---------------------------------------------------------------------------
template <int PASS_STEPS, int LDK>
__device__ __forceinline__ const unsigned short* srcstep(
    const unsigned short* __restrict__ s, int st) {
  return s + (size_t)(st / PASS_STEPS) * 128 * LDK + (st % PASS_STEPS) * 64;
}

template <int LDK>
__device__ __forceinline__ void loadBfrag(bf16x8 (&b)[4],
                                          const unsigned short* __restrict__ p,
                                          int m16, int quad, int wn) {
#pragma unroll
  for (int kk = 0; kk < 2; ++kk) {
    b[kk * 2 + 0] = *(const bf16x8*)(p + (size_t)(wn * 32 + m16) * LDK +
                                     kk * 32 + quad * 8);
    b[kk * 2 + 1] = *(const bf16x8*)(p + (size_t)(wn * 32 + 16 + m16) * LDK +
                                     kk * 32 + quad * 8);
  }
}

// One K-step: 4 A ds_reads + 8 MFMAs, B from registers.
template <int LDA>
__device__ __forceinline__ void mstep_reg(const unsigned short* A, int k0,
                                          const bf16x8 (&b)[4], floatx4* acc,
                                          int m16, int quad, int wm) {
#pragma unroll
  for (int kk = 0; kk < 64; kk += 32) {
    bf16x8 a0 = *(const bf16x8*)&A[(wm * 32 + m16) * LDA + k0 + kk + quad * 8];
    bf16x8 a1 =
        *(const bf16x8*)&A[(wm * 32 + 16 + m16) * LDA + k0 + kk + quad * 8];
    const int ib = (kk >> 5) * 2;
    acc[0] = __builtin_amdgcn_mfma_f32_16x16x32_bf16(a0, b[ib], acc[0], 0, 0, 0);
    acc[1] = __builtin_amdgcn_mfma_f32_16x16x32_bf16(a0, b[ib + 1], acc[1], 0, 0, 0);
    acc[2] = __builtin_amdgcn_mfma_f32_16x16x32_bf16(a1, b[ib], acc[2], 0, 0, 0);
    acc[3] = __builtin_amdgcn_mfma_f32_16x16x32_bf16(a1, b[ib + 1], acc[3], 0, 0, 0);
  }
}

// Full phase: T K-steps, NO barriers, 3-deep B register ring.
// Slot t%3 is consumed by mstep at iter t, then refilled with step t+3.
template <int T, int LDA, int PASS_STEPS, int LDK>
__device__ __forceinline__ void gemm_phase_reg(
    const unsigned short* A, const unsigned short* __restrict__ src,
    floatx4* acc, int m16, int quad, int wm, int wn) {
  bf16x8 b[3][4];
  loadBfrag<LDK>(b[0], srcstep<PASS_STEPS, LDK>(src, 0), m16, quad, wn);
  if (T > 1) loadBfrag<LDK>(b[1], srcstep<PASS_STEPS, LDK>(src, 1), m16, quad, wn);
  if (T > 2) loadBfrag<LDK>(b[2], srcstep<PASS_STEPS, LDK>(src, 2), m16, quad, wn);
#pragma unroll
  for (int t = 0; t < T; ++t) {
    mstep_reg<LDA>(A, (t % PASS_STEPS) * 64, b[t % 3],
                   acc + (t / PASS_STEPS) * 4, m16, quad, wm);
    if (t + 3 < T)
      loadBfrag<LDK>(b[t % 3], srcstep<PASS_STEPS, LDK>(src, t + 3), m16, quad,
                     wn);
  }
}

// ---------------------------------------------------------------------------
// K2 fused_mlp: 256 blocks x 64 rows x 512 threads, 7 barriers total.
// ---------------------------------------------------------------------------
__global__ __launch_bounds__(512, 2) void fused_mlp_kernel(
    const float* __restrict__ features, const int* __restrict__ ent_idx,
    const float* __restrict__ head_tab, const float* __restrict__ ent_tab,
    const float* __restrict__ w_cf, const float* __restrict__ w_fc,
    const float* __restrict__ w_ef, const float* __restrict__ w_fe,
    const float* __restrict__ b_c, const float* __restrict__ b_e,
    const unsigned short* __restrict__ wfT,
    const unsigned short* __restrict__ wuT, const float* __restrict__ bf_,
    const float* __restrict__ bu,
    const unsigned short* __restrict__ w0T, const float* __restrict__ b0,
    const unsigned short* __restrict__ w1T, const float* __restrict__ b1,
    const unsigned short* __restrict__ w2T, const float* __restrict__ b2,
    const int* __restrict__ target, float* __restrict__ out) {
  // regionA (shorts): [0,16896) feat/A_sh 64x264; [16896,25600) buf0 64x136;
  // [25600,34304) buf1 64x136. x0_sh 64x520 = 33280 aliases [0,33280).
  __shared__ __align__(16) unsigned short regionA[34304];   // 68.6 KB
  __shared__ __align__(16) unsigned short x1_sh[64 * 264];  // 33.8 KB
  __shared__ __align__(16) unsigned short w2_sh[2048];      //  4.0 KB
  __shared__ __align__(16) float cw_sh[512];                //  2.0 KB
  unsigned short* feat_sh = regionA;
  unsigned short* buf0 = regionA + 16896;
  unsigned short* buf1 = regionA + 25600;
  unsigned short* A_sh = regionA;   // 64x264: [cf2 | e] concat
  unsigned short* x0_sh = regionA;  // 64x520

  const int tid = threadIdx.x;
  const int r0 = blockIdx.x * 64;
  const int lane = tid & 63, wave = tid >> 6;
  const int m16 = lane & 15, quad = lane >> 4;
  const int wm = wave >> 2, wn = wave & 3;

  // ---- gather issue (earliest point; consumed after L1) ----
  const int grow = tid >> 3, gpart = tid & 7;
  const int gidx = ent_idx[r0 + grow];
  const float* hp = head_tab + (size_t)gidx * 128 + gpart * 16;
  const float* ep = ent_tab + (size_t)gidx * 128 + gpart * 16;
  float4 h4[4], e4[4];
#pragma unroll
  for (int j = 0; j < 4; ++j) {
    h4[j] = *(const float4*)(hp + j * 4);
    e4[j] = *(const float4*)(ep + j * 4);
  }
  // cross weights + w2 -> LDS
  if (tid < 128) {
    int a = tid >> 5, o = (tid & 31) * 4;
    const float* s = (a == 0) ? w_cf : (a == 1) ? w_fc : (a == 2) ? w_ef : w_fe;
    *(float4*)&cw_sh[a * 128 + o] = *(const float4*)(s + o);
  }
  if (tid < 256) *(uint4*)&w2_sh[tid * 8] = *(const uint4*)(w2T + tid * 8);

  // stage features fp32->bf16: 64 rows x 64 float4 = 4096, 8/thread
#pragma unroll
  for (int i = 0; i < 8; ++i) {
    int idx4 = i * 512 + tid;
    int row = idx4 >> 6, c = (idx4 & 63) * 4;
    float4 v = *(const float4*)(features + (size_t)(r0 + row) * 256 + c);
    uint2 o;
    o.x = (unsigned)f2bf(v.x) | ((unsigned)f2bf(v.y) << 16);
    o.y = (unsigned)f2bf(v.z) | ((unsigned)f2bf(v.w) << 16);
    *(uint2*)&feat_sh[row * 264 + c] = o;
  }
  PHASE_BAR();  // B1: feat/cw/w2 staging visible

  floatx4 acc[4];
  // ---- L1: cf0 = relu(feat @ Wf + bf), K=256, N=128 ----
#pragma unroll
  for (int j = 0; j < 4; ++j) acc[j] = (floatx4){0.f, 0.f, 0.f, 0.f};
  gemm_phase_reg<4, 264, 4, 256>(feat_sh, wfT, acc, m16, quad, wm, wn);
#pragma unroll
  for (int mi = 0; mi < 2; ++mi)
#pragma unroll
    for (int ni = 0; ni < 2; ++ni) {
      int col = wn * 32 + ni * 16 + m16;
      float bv = bf_[col];
#pragma unroll
      for (int r = 0; r < 4; ++r)
        buf0[(wm * 32 + mi * 16 + quad * 4 + r) * 136 + col] =
            f2bf(fmaxf(acc[mi * 2 + ni][r] + bv, 0.f));
    }
  PHASE_BAR();  // B2: all waves past feat reads; buf0 visible

  // ---- cross_compress x2 (consume gather) -> A_sh[:,128:256] ----
  // feat cols 128:256 now dead; A_sh[:,128:256] first read in x0 (post-B4).
  {
    float h[16], e[16];
#pragma unroll
    for (int j = 0; j < 4; ++j) {
      h[4 * j + 0] = h4[j].x; h[4 * j + 1] = h4[j].y;
      h[4 * j + 2] = h4[j].z; h[4 * j + 3] = h4[j].w;
      e[4 * j + 0] = e4[j].x; e[4 * j + 1] = e4[j].y;
      e[4 * j + 2] = e4[j].z; e[4 * j + 3] = e4[j].w;
    }
    const float bc = b_c[0], be = b_e[0];
#pragma unroll
    for (int it = 0; it < 2; ++it) {
      float d0 = 0.f, d1 = 0.f, d2 = 0.f, d3 = 0.f;
#pragma unroll
      for (int j = 0; j < 16; ++j) {
        float wcf = cw_sh[0 * 128 + gpart * 16 + j];
        float wfc = cw_sh[1 * 128 + gpart * 16 + j];
        float wef = cw_sh[2 * 128 + gpart * 16 + j];
        float wfe = cw_sh[3 * 128 + gpart * 16 + j];
        d0 += e[j] * wcf; d1 += h[j] * wfc;
        d2 += e[j] * wef; d3 += h[j] * wfe;
      }
#pragma unroll
      for (int s = 1; s < 8; s <<= 1) {
        d0 += __shfl_xor(d0, s); d1 += __shfl_xor(d1, s);
        d2 += __shfl_xor(d2, s); d3 += __shfl_xor(d3, s);
      }
#pragma unroll
      for (int j = 0; j < 16; ++j) {
        float nh = h[j] * d0 + e[j] * d1 + bc;
        float ne = h[j] * d2 + e[j] * d3 + be;
        h[j] = nh; e[j] = ne;
      }
    }
    uint4 o0, o1;
    unsigned* w = (unsigned*)&o0;
#pragma unroll
    for (int j = 0; j < 4; ++j)
      w[j] = (unsigned)f2bf(e[2 * j]) | ((unsigned)f2bf(e[2 * j + 1]) << 16);
    w = (unsigned*)&o1;
#pragma unroll
    for (int j = 0; j < 4; ++j)
      w[j] = (unsigned)f2bf(e[8 + 2 * j]) |
             ((unsigned)f2bf(e[8 + 2 * j + 1]) << 16);
    *(uint4*)&A_sh[grow * 264 + 128 + gpart * 16] = o0;
    *(uint4*)&A_sh[grow * 264 + 128 + gpart * 16 + 8] = o1;
  }

  // ---- L2: cf1 = relu(cf0 @ Wu + bu), K=128, N=128 ----
#pragma unroll
  for (int j = 0; j < 4; ++j) acc[j] = (floatx4){0.f, 0.f, 0.f, 0.f};
  gemm_phase_reg<2, 136, 2, 128>(buf0, wuT, acc, m16, quad, wm, wn);
#pragma unroll
  for (int mi = 0; mi < 2; ++mi)
#pragma unroll
    for (int ni = 0; ni < 2; ++ni) {
      int col = wn * 32 + ni * 16 + m16;
      float bv = bu[col];
#pragma unroll
      for (int r = 0; r < 4; ++r)
        buf1[(wm * 32 + mi * 16 + quad * 4 + r) * 136 + col] =
            f2bf(fmaxf(acc[mi * 2 + ni][r] + bv, 0.f));
    }
  PHASE_BAR();  // B3: buf1 + cross A_sh writes visible

  // ---- L3: cf2 = relu(cf1 @ Wu + bu) -> A_sh[:,0:128] ----
#pragma unroll
  for (int j = 0; j < 4; ++j) acc[j] = (floatx4){0.f, 0.f, 0.f, 0.f};
  gemm_phase_reg<2, 136, 2, 128>(buf1, wuT, acc, m16, quad, wm, wn);
#pragma unroll
  for (int mi = 0; mi < 2; ++mi)
#pragma unroll
    for (int ni = 0; ni < 2; ++ni) {
      int col = wn * 32 + ni * 16 + m16;
      float bv = bu[col];
#pragma unroll
      for (int r = 0; r < 4; ++r)
        A_sh[(wm * 32 + mi * 16 + quad * 4 + r) * 264 + col] =
            f2bf(fmaxf(acc[mi * 2 + ni][r] + bv, 0.f));
    }
  PHASE_BAR();  // B4: full A tile visible

  // ---- x0 = relu(A @ W0 + b0), K=256, N=512 as 4 n-passes ----
  floatx4 acc16[16];
#pragma unroll
  for (int j = 0; j < 16; ++j) acc16[j] = (floatx4){0.f, 0.f, 0.f, 0.f};
  gemm_phase_reg<16, 264, 4, 256>(A_sh, w0T, acc16, m16, quad, wm, wn);
  PHASE_BAR();  // B5: all A_sh reads drained before aliased x0_sh writes
#pragma unroll
  for (int np = 0; np < 4; ++np)
#pragma unroll
    for (int mi = 0; mi < 2; ++mi)
#pragma unroll
      for (int ni = 0; ni < 2; ++ni) {
        int col = np * 128 + wn * 32 + ni * 16 + m16;
        float bv = b0[col];
#pragma unroll
        for (int r = 0; r < 4; ++r)
          x0_sh[(wm * 32 + mi * 16 + quad * 4 + r) * 520 + col] =
              f2bf(fmaxf(acc16[np * 4 + mi * 2 + ni][r] + bv, 0.f));
      }
  PHASE_BAR();  // B6: x0_sh visible

  // ---- x1 = relu(x0 @ W1 + b1), K=512, N=256 as 2 n-passes ----
  floatx4 acc8[8];
#pragma unroll
  for (int j = 0; j < 8; ++j) acc8[j] = (floatx4){0.f, 0.f, 0.f, 0.f};
  gemm_phase_reg<16, 520, 8, 512>(x0_sh, w1T, acc8, m16, quad, wm, wn);
#pragma unroll
  for (int np = 0; np < 2; ++np)
#pragma unroll
    for (int mi = 0; mi < 2; ++mi)
#pragma unroll
      for (int ni = 0; ni < 2; ++ni) {
        int col = np * 128 + wn * 32 + ni * 16 + m16;
        float bv = b1[col];
#pragma unroll
        for (int r = 0; r < 4; ++r)
          x1_sh[(wm * 32 + mi * 16 + quad * 4 + r) * 264 + col] =
              f2bf(fmaxf(acc8[np * 4 + mi * 2 + ni][r] + bv, 0.f));
      }
  PHASE_BAR();  // B7: x1_sh visible

  // W2 GEMV + softmax: 8 lanes/row, 64 rows, 32 elems/lane
  {
    int row = tid >> 3, q = tid & 7;
    float p[8];
#pragma unroll
    for (int n = 0; n < 8; ++n) p[n] = 0.f;
#pragma unroll
    for (int jb = 0; jb < 4; ++jb) {
      bf16x8 xv = *(const bf16x8*)&x1_sh[row * 264 + q * 32 + jb * 8];
#pragma unroll
      for (int n = 0; n < 8; ++n) {
        bf16x8 wv = *(const bf16x8*)&w2_sh[n * 256 + q * 32 + jb * 8];
#pragma unroll
        for (int j = 0; j < 8; ++j) p[n] += (float)xv[j] * (float)wv[j];
      }
    }
#pragma unroll
    for (int s = 1; s < 8; s <<= 1)
#pragma unroll
      for (int n = 0; n < 8; ++n) p[n] += __shfl_xor(p[n], s);
    if (q == 0) {
      float mx = -1e30f;
#pragma unroll
      for (int n = 0; n < 8; ++n) {
        p[n] = fmaxf(p[n] + b2[n], 0.f);
        mx = fmaxf(mx, p[n]);
      }
      float sum = 0.f;
#pragma unroll
      for (int n = 0; n < 8; ++n) { p[n] = __expf(p[n] - mx); sum += p[n]; }
      const float inv = 1.f / sum;
      const int gr = r0 + row;
      float4 o0 = {p[0] * inv, p[1] * inv, p[2] * inv, p[3] * inv};
      float4 o1 = {p[4] * inv, p[5] * inv, p[6] * inv, p[7] * inv};
      *(float4*)(out + (size_t)gr * 8) = o0;
      *(float4*)(out + (size_t)gr * 8 + 4) = o1;
      out[16384 * 8 + gr] = (float)target[gr];
    }
  }
}

extern "C" void kernel_launch(void* const* d_in, const int* in_sizes, int n_in,
                              void* d_out, int out_size, void* d_ws, size_t ws_size,
                              hipStream_t stream) {
  const float* features = (const float*)d_in[0];
  const int* ent_idx    = (const int*)d_in[1];
  const int* target     = (const int*)d_in[2];
  const float* Wf  = (const float*)d_in[3];
  const float* bf_ = (const float*)d_in[4];
  const float* Wu  = (const float*)d_in[5];
  const float* bu  = (const float*)d_in[6];
  const float* w_cf = (const float*)d_in[7];
  const float* w_fc = (const float*)d_in[8];
  const float* w_ef = (const float*)d_in[9];
  const float* w_fe = (const float*)d_in[10];
  const float* b_c  = (const float*)d_in[11];
  const float* b_e  = (const float*)d_in[12];
  const float* head_tab = (const float*)d_in[13];
  const float* ent_tab  = (const float*)d_in[14];
  const float* W0 = (const float*)d_in[15];
  const float* b0 = (const float*)d_in[16];
  const float* W1 = (const float*)d_in[17];
  const float* b1 = (const float*)d_in[18];
  const float* W2 = (const float*)d_in[19];
  const float* b2 = (const float*)d_in[20];
  float* out = (float*)d_out;

  unsigned short* ws = (unsigned short*)d_ws;
  size_t off = 0;
  auto alloc = [&](size_t n) { unsigned short* p = ws + off; off += n; return p; };
  unsigned short* wfT  = alloc(32768);
  unsigned short* wuT  = alloc(16384);
  unsigned short* w0T  = alloc(131072);
  unsigned short* w1T  = alloc(131072);
  unsigned short* w2T  = alloc(2048);
  (void)ws_size; (void)in_sizes; (void)n_in; (void)out_size;

  // K1: weight transposes only
  prep_kernel<<<305, 256, 0, stream>>>(Wf, Wu, W0, W1, W2,
                                       wfT, wuT, w0T, w1T, w2T);
  // K2: full fused per-row pipeline, B direct from global
  fused_mlp_kernel<<<256, 512, 0, stream>>>(features, ent_idx, head_tab,
      ent_tab, w_cf, w_fc, w_ef, w_fe, b_c, b_e, wfT, wuT, bf_, bu,
      w0T, b0, w1T, b1, w2T, b2, target, out);
}

// Round 6
// 185.241 us; speedup vs baseline: 1.0720x; 1.0720x over previous
//
#include <hip/hip_runtime.h>
#include <hip/hip_bf16.h>

// CompanyOperationEvaluation R15: R12 structure + global_load_lds staging +
// full XOR-swizzle (T2+T3, rule #21 both-sides pattern).
//  - B staging: __builtin_amdgcn_global_load_lds width=16, LINEAR LDS dest
//    (chunk*16B), INVERSE-swizzled global source, swizzled ds_read. No
//    ds_writes in the staging path, no staging VGPR ring.
//  - All LDS tiles unpadded pow2 strides + chunk XOR: stored chunk =
//    logical ^ (row&7). A-tiles swizzled at epilogue-write and mstep-read.
//  - Per step: stage(t+1) issue -> mstep(buf[t&1]) -> vmcnt(0)+lgkmcnt(0)
//    -> s_barrier -> sched_barrier. Stage->drain distance = one mstep.
//  - Shape: 512 blocks x 256 thr (R12 best), LDS 70KB -> 2 blocks/CU.
// Lesson bank: (R2, reconfirmed R14) MFMA operands must come from LDS —
// per-wave global B frags are 16-line scatters, VMEM-issue-bound; (R5) 8
// MFMAs/wave/step; (R6) gather issued at top, consumed post-L1; (R13) L2
// request rate not the bottleneck; (R14) LDS+barrier removal without
// coalescing is worse. Theory here: LDS-pipe instr count + 8-way bank
// conflicts (strides 72/264/136/520 are all odd multiples of 16B) are the
// ~2300cyc/step serializer.

typedef __bf16 bf16x8 __attribute__((ext_vector_type(8)));
typedef float floatx4 __attribute__((ext_vector_type(4)));

__device__ __forceinline__ unsigned short f2bf(float x) {
  unsigned int u = __builtin_bit_cast(unsigned int, x);
  u = (u + 0x7FFFu + ((u >> 16) & 1u)) >> 16;
  return (unsigned short)u;
}

// chunk-XOR swizzle: col in shorts; xors the 16B-chunk index (bits 3..5)
// by (row&7). Valid for any sub-chunk offset (low 3 bits preserved).
__device__ __forceinline__ int sz(int row, int col) {
  return col ^ ((row & 7) << 3);
}

#define PHASE_BAR()                                                  \
  do {                                                               \
    asm volatile("s_waitcnt vmcnt(0) lgkmcnt(0)" ::: "memory");      \
    __builtin_amdgcn_s_barrier();                                    \
    __builtin_amdgcn_sched_barrier(0);                               \
  } while (0)

// ---------------------------------------------------------------------------
// K1 prep: blocks [0,304) 32x32 transpose tiles; block 304 W2.
// ---------------------------------------------------------------------------
__global__ __launch_bounds__(256) void prep_kernel(
    const float* __restrict__ Wf, const float* __restrict__ Wu,
    const float* __restrict__ W0, const float* __restrict__ W1,
    const float* __restrict__ W2,
    unsigned short* __restrict__ wfT, unsigned short* __restrict__ wuT,
    unsigned short* __restrict__ w0T, unsigned short* __restrict__ w1T,
    unsigned short* __restrict__ w2T) {
  __shared__ unsigned short tile[32][34];
  const int bid = blockIdx.x, tid = threadIdx.x;
  if (bid < 304) {
    int t = bid;
    const float* src; unsigned short* dst; int N, K, kt, nt;
    if (t < 32)       { src = Wf; dst = wfT; N = 128; K = 256; kt = t >> 2;       nt = t & 3; }
    else if (t < 48)  { t -= 32;  src = Wu; dst = wuT; N = 128; K = 128; kt = t >> 2; nt = t & 3; }
    else if (t < 176) { t -= 48;  src = W0; dst = w0T; N = 512; K = 256; kt = t >> 4; nt = t & 15; }
    else              { t -= 176; src = W1; dst = w1T; N = 256; K = 512; kt = t >> 3; nt = t & 7; }
    {
      int r = tid >> 3, cg = (tid & 7) * 4;
      float4 v = *(const float4*)(src + (size_t)(kt * 32 + r) * N + nt * 32 + cg);
      tile[r][cg + 0] = f2bf(v.x); tile[r][cg + 1] = f2bf(v.y);
      tile[r][cg + 2] = f2bf(v.z); tile[r][cg + 3] = f2bf(v.w);
    }
    __syncthreads();
    {
      int rp = tid >> 3, cg = (tid & 7) * 4;
      uint2 o;
      o.x = (unsigned)tile[cg + 0][rp] | ((unsigned)tile[cg + 1][rp] << 16);
      o.y = (unsigned)tile[cg + 2][rp] | ((unsigned)tile[cg + 3][rp] << 16);
      *(uint2*)(dst + (size_t)(nt * 32 + rp) * K + kt * 32 + cg) = o;
    }
  } else {
#pragma unroll
    for (int i = 0; i < 8; ++i) {
      int g = tid * 8 + i, k = g >> 3, n = g & 7;
      w2T[n * 256 + k] = f2bf(W2[g]);
    }
  }
}

// ---------------------------------------------------------------------------
// Staging: one 128x64 B step-tile (16KB) via global_load_lds width=16.
// LDS dest linear (chunk*8 shorts); global source inverse-swizzled so that
// stored chunk (row, seg) holds logical column chunk seg^(row&7).
// ---------------------------------------------------------------------------
template <int LDK>
__device__ __forceinline__ void stageB(unsigned short* dstbase,
                                       const unsigned short* __restrict__ src,
                                       int tid) {
#pragma unroll
  for (int i = 0; i < 4; ++i) {
    int chunk = i * 256 + tid;
    int row = chunk >> 3, segs = chunk & 7;
    int segl = segs ^ (row & 7);
    const unsigned short* g = src + (size_t)row * LDK + segl * 8;
    unsigned short* d = dstbase + chunk * 8;
    __builtin_amdgcn_global_load_lds((const unsigned int*)g, (unsigned int*)d,
                                     16, 0, 0);
  }
}

template <int PASS_STEPS, int LDK>
__device__ __forceinline__ const unsigned short* srcstep(
    const unsigned short* __restrict__ s, int st) {
  return s + (size_t)(st / PASS_STEPS) * 128 * LDK + (st % PASS_STEPS) * 64;
}

// One K-step: 4 A ds_reads + 4 B ds_reads + 8 MFMAs (all reads swizzled).
template <int LDA>
__device__ __forceinline__ void mstep(const unsigned short* A,
                                      const unsigned short* bt, int k0,
                                      floatx4* acc, int m16, int quad,
                                      int wave) {
#pragma unroll
  for (int kk = 0; kk < 64; kk += 32) {
    const int ca = k0 + kk + quad * 8;
    const int cb = kk + quad * 8;
    const int ra0 = m16, ra1 = 16 + m16;
    const int rb0 = wave * 32 + m16, rb1 = wave * 32 + 16 + m16;
    bf16x8 a0 = *(const bf16x8*)&A[ra0 * LDA + sz(ra0, ca)];
    bf16x8 a1 = *(const bf16x8*)&A[ra1 * LDA + sz(ra1, ca)];
    bf16x8 b0 = *(const bf16x8*)&bt[rb0 * 64 + sz(rb0, cb)];
    bf16x8 b1 = *(const bf16x8*)&bt[rb1 * 64 + sz(rb1, cb)];
    acc[0] = __builtin_amdgcn_mfma_f32_16x16x32_bf16(a0, b0, acc[0], 0, 0, 0);
    acc[1] = __builtin_amdgcn_mfma_f32_16x16x32_bf16(a0, b1, acc[1], 0, 0, 0);
    acc[2] = __builtin_amdgcn_mfma_f32_16x16x32_bf16(a1, b0, acc[2], 0, 0, 0);
    acc[3] = __builtin_amdgcn_mfma_f32_16x16x32_bf16(a1, b1, acc[3], 0, 0, 0);
  }
}

// Pipelined phase: stage(t+1) issue / mstep(buf t&1) / vmcnt0+lgkm0+barrier.
// WAR safety: stage target buf[(t+1)&1] was last read at iter t-1, whose
// reads drained at that iter's barrier.
template <int T, int LDA, int PASS_STEPS, int LDK>
__device__ __forceinline__ void gemm_phase(
    const unsigned short* A, const unsigned short* __restrict__ src,
    unsigned short* b_sh, floatx4* acc, int tid, int m16, int quad, int wave) {
  stageB<LDK>(b_sh, srcstep<PASS_STEPS, LDK>(src, 0), tid);
  PHASE_BAR();
#pragma unroll
  for (int t = 0; t < T; ++t) {
    if (t + 1 < T)
      stageB<LDK>(b_sh + ((t + 1) & 1) * 8192,
                  srcstep<PASS_STEPS, LDK>(src, t + 1), tid);
    mstep<LDA>(A, b_sh + (t & 1) * 8192, (t % PASS_STEPS) * 64,
               acc + (t / PASS_STEPS) * 4, m16, quad, wave);
    PHASE_BAR();
  }
}

// ---------------------------------------------------------------------------
// K2 fused_mlp: 512 blocks x 32 rows x 256 threads.
// ---------------------------------------------------------------------------
__global__ __launch_bounds__(256, 2) void fused_mlp_kernel(
    const float* __restrict__ features, const int* __restrict__ ent_idx,
    const float* __restrict__ head_tab, const float* __restrict__ ent_tab,
    const float* __restrict__ w_cf, const float* __restrict__ w_fc,
    const float* __restrict__ w_ef, const float* __restrict__ w_fe,
    const float* __restrict__ b_c, const float* __restrict__ b_e,
    const unsigned short* __restrict__ wfT,
    const unsigned short* __restrict__ wuT, const float* __restrict__ bf_,
    const float* __restrict__ bu,
    const unsigned short* __restrict__ w0T, const float* __restrict__ b0,
    const unsigned short* __restrict__ w1T, const float* __restrict__ b1,
    const unsigned short* __restrict__ w2T, const float* __restrict__ b2,
    const int* __restrict__ target, float* __restrict__ out) {
  // regionA (shorts): [0,8192) feat/A_sh 32x256; [8192,12288) buf0 32x128;
  // [12288,16384) buf1 32x128. x0_sh 32x512 = 16384 aliases all of regionA.
  __shared__ __align__(16) unsigned short regionA[16384];   // 32 KB
  __shared__ __align__(16) unsigned short b_sh[2 * 8192];   // 32 KB (2 bufs)
  __shared__ __align__(16) unsigned short w2_sh[2048];      //  4 KB
  __shared__ __align__(16) float cw_sh[512];                //  2 KB
  unsigned short* feat_sh = regionA;
  unsigned short* buf0 = regionA + 8192;
  unsigned short* buf1 = regionA + 12288;
  unsigned short* A_sh = regionA;   // 32x256: [cf2 | e] concat (swizzled)
  unsigned short* x0_sh = regionA;  // 32x512 (swizzled)
  unsigned short* x1_sh = b_sh;     // 32x264 = 8448 <= 16384 (UNswizzled)

  const int tid = threadIdx.x;
  const int r0 = blockIdx.x * 32;
  const int lane = tid & 63, wave = tid >> 6;
  const int m16 = lane & 15, quad = lane >> 4;

  // ---- gather issue (earliest point; consumed after L1) ----
  const int grow = tid >> 3, gpart = tid & 7;
  const int gidx = ent_idx[r0 + grow];
  const float* hp = head_tab + (size_t)gidx * 128 + gpart * 16;
  const float* ep = ent_tab + (size_t)gidx * 128 + gpart * 16;
  float4 h4[4], e4[4];
#pragma unroll
  for (int j = 0; j < 4; ++j) {
    h4[j] = *(const float4*)(hp + j * 4);
    e4[j] = *(const float4*)(ep + j * 4);
  }
  // cross weights + w2 -> LDS
  if (tid < 128) {
    int a = tid >> 5, o = (tid & 31) * 4;
    const float* s = (a == 0) ? w_cf : (a == 1) ? w_fc : (a == 2) ? w_ef : w_fe;
    *(float4*)&cw_sh[a * 128 + o] = *(const float4*)(s + o);
  }
  *(uint4*)&w2_sh[tid * 8] = *(const uint4*)(w2T + tid * 8);

  // stage features fp32->bf16 (swizzled writes): 2048 float4, 8/thread
#pragma unroll
  for (int i = 0; i < 8; ++i) {
    int idx4 = i * 256 + tid;
    int row = idx4 >> 6, c = (idx4 & 63) * 4;
    float4 v = *(const float4*)(features + (size_t)(r0 + row) * 256 + c);
    uint2 o;
    o.x = (unsigned)f2bf(v.x) | ((unsigned)f2bf(v.y) << 16);
    o.y = (unsigned)f2bf(v.z) | ((unsigned)f2bf(v.w) << 16);
    *(uint2*)&feat_sh[row * 256 + sz(row, c)] = o;
  }

  floatx4 acc[4];
  // ---- L1: cf0 = relu(feat @ Wf + bf), K=256, N=128 ----
#pragma unroll
  for (int j = 0; j < 4; ++j) acc[j] = (floatx4){0.f, 0.f, 0.f, 0.f};
  gemm_phase<4, 256, 4, 256>(feat_sh, wfT, b_sh, acc, tid, m16, quad, wave);
#pragma unroll
  for (int mi = 0; mi < 2; ++mi)
#pragma unroll
    for (int ni = 0; ni < 2; ++ni) {
      int col = wave * 32 + ni * 16 + m16;
      float bv = bf_[col];
#pragma unroll
      for (int r = 0; r < 4; ++r) {
        int row = mi * 16 + quad * 4 + r;
        buf0[row * 128 + sz(row, col)] =
            f2bf(fmaxf(acc[mi * 2 + ni][r] + bv, 0.f));
      }
    }

  // ---- cross_compress x2 (consume gather) -> A_sh[:,128:256] ----
  // feat cols 128:256 dead (L1's final barrier drained all A reads); next
  // reader of A_sh[:,128:256] is x0, behind several barriers.
  {
    float h[16], e[16];
#pragma unroll
    for (int j = 0; j < 4; ++j) {
      h[4 * j + 0] = h4[j].x; h[4 * j + 1] = h4[j].y;
      h[4 * j + 2] = h4[j].z; h[4 * j + 3] = h4[j].w;
      e[4 * j + 0] = e4[j].x; e[4 * j + 1] = e4[j].y;
      e[4 * j + 2] = e4[j].z; e[4 * j + 3] = e4[j].w;
    }
    const float bc = b_c[0], be = b_e[0];
#pragma unroll
    for (int it = 0; it < 2; ++it) {
      float d0 = 0.f, d1 = 0.f, d2 = 0.f, d3 = 0.f;
#pragma unroll
      for (int j = 0; j < 16; ++j) {
        float wcf = cw_sh[0 * 128 + gpart * 16 + j];
        float wfc = cw_sh[1 * 128 + gpart * 16 + j];
        float wef = cw_sh[2 * 128 + gpart * 16 + j];
        float wfe = cw_sh[3 * 128 + gpart * 16 + j];
        d0 += e[j] * wcf; d1 += h[j] * wfc;
        d2 += e[j] * wef; d3 += h[j] * wfe;
      }
#pragma unroll
      for (int s = 1; s < 8; s <<= 1) {
        d0 += __shfl_xor(d0, s); d1 += __shfl_xor(d1, s);
        d2 += __shfl_xor(d2, s); d3 += __shfl_xor(d3, s);
      }
#pragma unroll
      for (int j = 0; j < 16; ++j) {
        float nh = h[j] * d0 + e[j] * d1 + bc;
        float ne = h[j] * d2 + e[j] * d3 + be;
        h[j] = nh; e[j] = ne;
      }
    }
    uint4 o0, o1;
    unsigned* w = (unsigned*)&o0;
#pragma unroll
    for (int j = 0; j < 4; ++j)
      w[j] = (unsigned)f2bf(e[2 * j]) | ((unsigned)f2bf(e[2 * j + 1]) << 16);
    w = (unsigned*)&o1;
#pragma unroll
    for (int j = 0; j < 4; ++j)
      w[j] = (unsigned)f2bf(e[8 + 2 * j]) |
             ((unsigned)f2bf(e[8 + 2 * j + 1]) << 16);
    const int c0 = 128 + gpart * 16;
    *(uint4*)&A_sh[grow * 256 + sz(grow, c0)] = o0;
    *(uint4*)&A_sh[grow * 256 + sz(grow, c0 + 8)] = o1;
  }

  // ---- L2: cf1 = relu(cf0 @ Wu + bu), K=128, N=128 ----
#pragma unroll
  for (int j = 0; j < 4; ++j) acc[j] = (floatx4){0.f, 0.f, 0.f, 0.f};
  gemm_phase<2, 128, 2, 128>(buf0, wuT, b_sh, acc, tid, m16, quad, wave);
#pragma unroll
  for (int mi = 0; mi < 2; ++mi)
#pragma unroll
    for (int ni = 0; ni < 2; ++ni) {
      int col = wave * 32 + ni * 16 + m16;
      float bv = bu[col];
#pragma unroll
      for (int r = 0; r < 4; ++r) {
        int row = mi * 16 + quad * 4 + r;
        buf1[row * 128 + sz(row, col)] =
            f2bf(fmaxf(acc[mi * 2 + ni][r] + bv, 0.f));
      }
    }

  // ---- L3: cf2 = relu(cf1 @ Wu + bu) -> A_sh[:,0:128] ----
  // b_sh buffers still hold wuT steps 0,1 from L2 (same swizzled layout).
#pragma unroll
  for (int j = 0; j < 4; ++j) acc[j] = (floatx4){0.f, 0.f, 0.f, 0.f};
  PHASE_BAR();  // buf1 (L2 epilogue ds_writes) visible to all waves
  mstep<128>(buf1, b_sh, 0, acc, m16, quad, wave);
  mstep<128>(buf1, b_sh + 8192, 64, acc, m16, quad, wave);
  PHASE_BAR();  // drain b_sh reads before x0's stage(0) overwrites b_sh
#pragma unroll
  for (int mi = 0; mi < 2; ++mi)
#pragma unroll
    for (int ni = 0; ni < 2; ++ni) {
      int col = wave * 32 + ni * 16 + m16;
      float bv = bu[col];
#pragma unroll
      for (int r = 0; r < 4; ++r) {
        int row = mi * 16 + quad * 4 + r;
        A_sh[row * 256 + sz(row, col)] =
            f2bf(fmaxf(acc[mi * 2 + ni][r] + bv, 0.f));
      }
    }

  // ---- x0 = relu(A @ W0 + b0), K=256, N=512 as 4 n-passes ----
  floatx4 acc16[16];
#pragma unroll
  for (int j = 0; j < 16; ++j) acc16[j] = (floatx4){0.f, 0.f, 0.f, 0.f};
  gemm_phase<16, 256, 4, 256>(A_sh, w0T, b_sh, acc16, tid, m16, quad, wave);
  // epilogue -> x0_sh (overwrites regionA; all A reads drained at final bar)
#pragma unroll
  for (int np = 0; np < 4; ++np)
#pragma unroll
    for (int mi = 0; mi < 2; ++mi)
#pragma unroll
      for (int ni = 0; ni < 2; ++ni) {
        int col = np * 128 + wave * 32 + ni * 16 + m16;
        float bv = b0[col];
#pragma unroll
        for (int r = 0; r < 4; ++r) {
          int row = mi * 16 + quad * 4 + r;
          x0_sh[row * 512 + sz(row, col)] =
              f2bf(fmaxf(acc16[np * 4 + mi * 2 + ni][r] + bv, 0.f));
        }
      }

  // ---- x1 = relu(x0 @ W1 + b1), K=512, N=256 as 2 n-passes ----
  // x1's stage(0) is safe: x0's final barrier drained all b_sh reads.
  // x1's first PHASE_BAR flushes the x0_sh epilogue ds_writes.
  floatx4 acc8[8];
#pragma unroll
  for (int j = 0; j < 8; ++j) acc8[j] = (floatx4){0.f, 0.f, 0.f, 0.f};
  gemm_phase<16, 512, 8, 512>(x0_sh, w1T, b_sh, acc8, tid, m16, quad, wave);
  // epilogue -> x1_sh aliased over b_sh (all b_sh reads drained at final bar)
#pragma unroll
  for (int np = 0; np < 2; ++np)
#pragma unroll
    for (int mi = 0; mi < 2; ++mi)
#pragma unroll
      for (int ni = 0; ni < 2; ++ni) {
        int col = np * 128 + wave * 32 + ni * 16 + m16;
        float bv = b1[col];
#pragma unroll
        for (int r = 0; r < 4; ++r)
          x1_sh[(mi * 16 + quad * 4 + r) * 264 + col] =
              f2bf(fmaxf(acc8[np * 4 + mi * 2 + ni][r] + bv, 0.f));
      }
  PHASE_BAR();

  // W2 GEMV + softmax: 8 lanes/row, 32 elems/lane
  {
    int row = tid >> 3, q = tid & 7;
    float p[8];
#pragma unroll
    for (int n = 0; n < 8; ++n) p[n] = 0.f;
#pragma unroll
    for (int jb = 0; jb < 4; ++jb) {
      bf16x8 xv = *(const bf16x8*)&x1_sh[row * 264 + q * 32 + jb * 8];
#pragma unroll
      for (int n = 0; n < 8; ++n) {
        bf16x8 wv = *(const bf16x8*)&w2_sh[n * 256 + q * 32 + jb * 8];
#pragma unroll
        for (int j = 0; j < 8; ++j) p[n] += (float)xv[j] * (float)wv[j];
      }
    }
#pragma unroll
    for (int s = 1; s < 8; s <<= 1)
#pragma unroll
      for (int n = 0; n < 8; ++n) p[n] += __shfl_xor(p[n], s);
    if (q == 0) {
      float mx = -1e30f;
#pragma unroll
      for (int n = 0; n < 8; ++n) {
        p[n] = fmaxf(p[n] + b2[n], 0.f);
        mx = fmaxf(mx, p[n]);
      }
      float sum = 0.f;
#pragma unroll
      for (int n = 0; n < 8; ++n) { p[n] = __expf(p[n] - mx); sum += p[n]; }
      const float inv = 1.f / sum;
      const int gr = r0 + row;
      float4 o0 = {p[0] * inv, p[1] * inv, p[2] * inv, p[3] * inv};
      float4 o1 = {p[4] * inv, p[5] * inv, p[6] * inv, p[7] * inv};
      *(float4*)(out + (size_t)gr * 8) = o0;
      *(float4*)(out + (size_t)gr * 8 + 4) = o1;
      out[16384 * 8 + gr] = (float)target[gr];
    }
  }
}

extern "C" void kernel_launch(void* const* d_in, const int* in_sizes, int n_in,
                              void* d_out, int out_size, void* d_ws, size_t ws_size,
                              hipStream_t stream) {
  const float* features = (const float*)d_in[0];
  const int* ent_idx    = (const int*)d_in[1];
  const int* target     = (const int*)d_in[2];
  const float* Wf  = (const float*)d_in[3];
  const float* bf_ = (const float*)d_in[4];
  const float* Wu  = (const float*)d_in[5];
  const float* bu  = (const float*)d_in[6];
  const float* w_cf = (const float*)d_in[7];
  const float* w_fc = (const float*)d_in[8];
  const float* w_ef = (const float*)d_in[9];
  const float* w_fe = (const float*)d_in[10];
  const float* b_c  = (const float*)d_in[11];
  const float* b_e  = (const float*)d_in[12];
  const float* head_tab = (const float*)d_in[13];
  const float* ent_tab  = (const float*)d_in[14];
  const float* W0 = (const float*)d_in[15];
  const float* b0 = (const float*)d_in[16];
  const float* W1 = (const float*)d_in[17];
  const float* b1 = (const float*)d_in[18];
  const float* W2 = (const float*)d_in[19];
  const float* b2 = (const float*)d_in[20];
  float* out = (float*)d_out;

  unsigned short* ws = (unsigned short*)d_ws;
  size_t off = 0;
  auto alloc = [&](size_t n) { unsigned short* p = ws + off; off += n; return p; };
  unsigned short* wfT  = alloc(32768);
  unsigned short* wuT  = alloc(16384);
  unsigned short* w0T  = alloc(131072);
  unsigned short* w1T  = alloc(131072);
  unsigned short* w2T  = alloc(2048);
  (void)ws_size; (void)in_sizes; (void)n_in; (void)out_size;

  // K1: weight transposes only
  prep_kernel<<<305, 256, 0, stream>>>(Wf, Wu, W0, W1, W2,
                                       wfT, wuT, w0T, w1T, w2T);
  // K2: full fused per-row pipeline (gather+cross + cf chain + x0 + x1 +
  // W2/softmax), global_load_lds staging + swizzled LDS
  fused_mlp_kernel<<<512, 256, 0, stream>>>(features, ent_idx, head_tab,
      ent_tab, w_cf, w_fc, w_ef, w_fe, b_c, b_e, wfT, wuT, bf_, bu,
      w0T, b0, w1T, b1, w2T, b2, target, out);
}

// Round 7
// 181.743 us; speedup vs baseline: 1.0927x; 1.0192x over previous
//
#include <hip/hip_runtime.h>
#include <hip/hip_bf16.h>

// CompanyOperationEvaluation R16: R15 + counted-vmcnt deep pipeline (T4).
//  - b_sh TRIPLE-buffered (3 x 16KB). Step t: issue stage(t+2) -> buf[(t+2)%3];
//    mstep(buf[t%3]); s_waitcnt vmcnt(4) lgkmcnt(0); s_barrier.
//    vmcnt(4) leaves stage(t+2)'s 4 loads in flight across the barrier;
//    in-order VMEM retirement proves stage(t+1) landed. vmcnt(0) only at the
//    last two steps of each phase. Lookahead = 1 step + 1 mstep (~1400cyc)
//    >> L2 latency -> per-step drain stall eliminated.
//  - LDS exactly 81920 B (regionA 32KB + 48KB b_sh) -> 2 blocks/CU:
//    cross-weights staged into regionA's buf1 slot (free until L2 epilogue);
//    W2 GEMV reads w2T direct from global (4KB, L2-hot, tail-phase only).
//  - Known cost: in-order vmcnt forces the early gather drain at L1's first
//    counted wait (~300cyc, once).
// Lesson bank: (R2/R14) MFMA operands from LDS, staged via global_load_lds;
// (R5) 8 MFMAs/wave/step; (R6) gather issue-early; (R13) L2 request rate not
// the limit; (R15) swizzle+gld_lds alone doesn't move 42us -> per-step
// vmcnt(0) drain is the residual theory this round tests.

typedef __bf16 bf16x8 __attribute__((ext_vector_type(8)));
typedef float floatx4 __attribute__((ext_vector_type(4)));

__device__ __forceinline__ unsigned short f2bf(float x) {
  unsigned int u = __builtin_bit_cast(unsigned int, x);
  u = (u + 0x7FFFu + ((u >> 16) & 1u)) >> 16;
  return (unsigned short)u;
}

// chunk-XOR swizzle: col in shorts; xors the 16B-chunk index (bits 3..5)
// by (row&7). Valid for any sub-chunk offset (low 3 bits preserved).
__device__ __forceinline__ int sz(int row, int col) {
  return col ^ ((row & 7) << 3);
}

#define BAR_VM(N)                                                      \
  do {                                                                 \
    asm volatile("s_waitcnt vmcnt(" #N ") lgkmcnt(0)" ::: "memory");   \
    __builtin_amdgcn_s_barrier();                                      \
    __builtin_amdgcn_sched_barrier(0);                                 \
  } while (0)

// ---------------------------------------------------------------------------
// K1 prep: blocks [0,304) 32x32 transpose tiles; block 304 W2.
// ---------------------------------------------------------------------------
__global__ __launch_bounds__(256) void prep_kernel(
    const float* __restrict__ Wf, const float* __restrict__ Wu,
    const float* __restrict__ W0, const float* __restrict__ W1,
    const float* __restrict__ W2,
    unsigned short* __restrict__ wfT, unsigned short* __restrict__ wuT,
    unsigned short* __restrict__ w0T, unsigned short* __restrict__ w1T,
    unsigned short* __restrict__ w2T) {
  __shared__ unsigned short tile[32][34];
  const int bid = blockIdx.x, tid = threadIdx.x;
  if (bid < 304) {
    int t = bid;
    const float* src; unsigned short* dst; int N, K, kt, nt;
    if (t < 32)       { src = Wf; dst = wfT; N = 128; K = 256; kt = t >> 2;       nt = t & 3; }
    else if (t < 48)  { t -= 32;  src = Wu; dst = wuT; N = 128; K = 128; kt = t >> 2; nt = t & 3; }
    else if (t < 176) { t -= 48;  src = W0; dst = w0T; N = 512; K = 256; kt = t >> 4; nt = t & 15; }
    else              { t -= 176; src = W1; dst = w1T; N = 256; K = 512; kt = t >> 3; nt = t & 7; }
    {
      int r = tid >> 3, cg = (tid & 7) * 4;
      float4 v = *(const float4*)(src + (size_t)(kt * 32 + r) * N + nt * 32 + cg);
      tile[r][cg + 0] = f2bf(v.x); tile[r][cg + 1] = f2bf(v.y);
      tile[r][cg + 2] = f2bf(v.z); tile[r][cg + 3] = f2bf(v.w);
    }
    __syncthreads();
    {
      int rp = tid >> 3, cg = (tid & 7) * 4;
      uint2 o;
      o.x = (unsigned)tile[cg + 0][rp] | ((unsigned)tile[cg + 1][rp] << 16);
      o.y = (unsigned)tile[cg + 2][rp] | ((unsigned)tile[cg + 3][rp] << 16);
      *(uint2*)(dst + (size_t)(nt * 32 + rp) * K + kt * 32 + cg) = o;
    }
  } else {
#pragma unroll
    for (int i = 0; i < 8; ++i) {
      int g = tid * 8 + i, k = g >> 3, n = g & 7;
      w2T[n * 256 + k] = f2bf(W2[g]);
    }
  }
}

// ---------------------------------------------------------------------------
// Staging: one 128x64 B step-tile (16KB) via global_load_lds width=16.
// LDS dest linear (chunk*16B = wave-uniform base + lane*16); global source
// inverse-swizzled so stored chunk (row,seg) holds logical chunk seg^(row&7).
// 4 gld_lds instructions per thread per stage call.
// ---------------------------------------------------------------------------
template <int LDK>
__device__ __forceinline__ void stageB(unsigned short* dstbase,
                                       const unsigned short* __restrict__ src,
                                       int tid) {
#pragma unroll
  for (int i = 0; i < 4; ++i) {
    int chunk = i * 256 + tid;
    int row = chunk >> 3, segs = chunk & 7;
    int segl = segs ^ (row & 7);
    const unsigned short* g = src + (size_t)row * LDK + segl * 8;
    unsigned short* d = dstbase + chunk * 8;
    __builtin_amdgcn_global_load_lds((const unsigned int*)g, (unsigned int*)d,
                                     16, 0, 0);
  }
}

template <int PASS_STEPS, int LDK>
__device__ __forceinline__ const unsigned short* srcstep(
    const unsigned short* __restrict__ s, int st) {
  return s + (size_t)(st / PASS_STEPS) * 128 * LDK + (st % PASS_STEPS) * 64;
}

// One K-step: 4 A ds_reads + 4 B ds_reads + 8 MFMAs (all reads swizzled).
template <int LDA>
__device__ __forceinline__ void mstep(const unsigned short* A,
                                      const unsigned short* bt, int k0,
                                      floatx4* acc, int m16, int quad,
                                      int wave) {
#pragma unroll
  for (int kk = 0; kk < 64; kk += 32) {
    const int ca = k0 + kk + quad * 8;
    const int cb = kk + quad * 8;
    const int ra0 = m16, ra1 = 16 + m16;
    const int rb0 = wave * 32 + m16, rb1 = wave * 32 + 16 + m16;
    bf16x8 a0 = *(const bf16x8*)&A[ra0 * LDA + sz(ra0, ca)];
    bf16x8 a1 = *(const bf16x8*)&A[ra1 * LDA + sz(ra1, ca)];
    bf16x8 b0 = *(const bf16x8*)&bt[rb0 * 64 + sz(rb0, cb)];
    bf16x8 b1 = *(const bf16x8*)&bt[rb1 * 64 + sz(rb1, cb)];
    acc[0] = __builtin_amdgcn_mfma_f32_16x16x32_bf16(a0, b0, acc[0], 0, 0, 0);
    acc[1] = __builtin_amdgcn_mfma_f32_16x16x32_bf16(a0, b1, acc[1], 0, 0, 0);
    acc[2] = __builtin_amdgcn_mfma_f32_16x16x32_bf16(a1, b0, acc[2], 0, 0, 0);
    acc[3] = __builtin_amdgcn_mfma_f32_16x16x32_bf16(a1, b1, acc[3], 0, 0, 0);
  }
}

// Pipelined phase, triple-buffered, lookahead-2, counted vmcnt.
// Iter t: issue stage(t+2) -> buf[(t+2)%3]; mstep(buf[t%3]);
//         wait vmcnt(4) [stage(t+2) in flight; in-order retirement proves
//         stage(t+1) landed] + lgkmcnt(0); s_barrier.
// WAR: stage(t+2)'s target buf was last read by mstep(t-1), drained at that
// iter's lgkmcnt(0)+barrier, which precedes this issue in program order.
template <int T, int LDA, int PASS_STEPS, int LDK>
__device__ __forceinline__ void gemm_phase(
    const unsigned short* A, const unsigned short* __restrict__ src,
    unsigned short* b_sh, floatx4* acc, int tid, int m16, int quad, int wave) {
  stageB<LDK>(b_sh, srcstep<PASS_STEPS, LDK>(src, 0), tid);
  if (T > 1) {
    stageB<LDK>(b_sh + 8192, srcstep<PASS_STEPS, LDK>(src, 1), tid);
    BAR_VM(4);  // stage0 landed; stage1 stays in flight
  } else {
    BAR_VM(0);
  }
#pragma unroll
  for (int t = 0; t < T; ++t) {
    if (t + 2 < T)
      stageB<LDK>(b_sh + ((t + 2) % 3) * 8192,
                  srcstep<PASS_STEPS, LDK>(src, t + 2), tid);
    mstep<LDA>(A, b_sh + (t % 3) * 8192, (t % PASS_STEPS) * 64,
               acc + (t / PASS_STEPS) * 4, m16, quad, wave);
    if (t + 2 < T) {
      BAR_VM(4);  // stage(t+1) landed; stage(t+2) in flight
    } else {
      BAR_VM(0);  // phase tail: drain everything
    }
  }
}

// ---------------------------------------------------------------------------
// K2 fused_mlp: 512 blocks x 32 rows x 256 threads. LDS = 81920 B exactly.
// ---------------------------------------------------------------------------
__global__ __launch_bounds__(256, 2) void fused_mlp_kernel(
    const float* __restrict__ features, const int* __restrict__ ent_idx,
    const float* __restrict__ head_tab, const float* __restrict__ ent_tab,
    const float* __restrict__ w_cf, const float* __restrict__ w_fc,
    const float* __restrict__ w_ef, const float* __restrict__ w_fe,
    const float* __restrict__ b_c, const float* __restrict__ b_e,
    const unsigned short* __restrict__ wfT,
    const unsigned short* __restrict__ wuT, const float* __restrict__ bf_,
    const float* __restrict__ bu,
    const unsigned short* __restrict__ w0T, const float* __restrict__ b0,
    const unsigned short* __restrict__ w1T, const float* __restrict__ b1,
    const unsigned short* __restrict__ w2T, const float* __restrict__ b2,
    const int* __restrict__ target, float* __restrict__ out) {
  // regionA (shorts): [0,8192) feat/A_sh 32x256; [8192,12288) buf0 32x128;
  // [12288,16384) buf1 32x128 (cw floats parked here until L2 epilogue).
  // x0_sh 32x512 = 16384 aliases all of regionA.
  __shared__ __align__(16) unsigned short regionA[16384];   // 32 KB
  __shared__ __align__(16) unsigned short b_sh[3 * 8192];   // 48 KB (3 bufs)
  unsigned short* feat_sh = regionA;
  unsigned short* buf0 = regionA + 8192;
  unsigned short* buf1 = regionA + 12288;
  unsigned short* A_sh = regionA;   // 32x256: [cf2 | e] concat (swizzled)
  unsigned short* x0_sh = regionA;  // 32x512 (swizzled)
  unsigned short* x1_sh = b_sh;     // 32x264 = 8448 shorts (UNswizzled)
  float* cw_p = (float*)buf1;       // 512 floats; dead before L2 epilogue

  const int tid = threadIdx.x;
  const int r0 = blockIdx.x * 32;
  const int lane = tid & 63, wave = tid >> 6;
  const int m16 = lane & 15, quad = lane >> 4;

  // ---- gather issue (earliest point; consumed after L1) ----
  const int grow = tid >> 3, gpart = tid & 7;
  const int gidx = ent_idx[r0 + grow];
  const float* hp = head_tab + (size_t)gidx * 128 + gpart * 16;
  const float* ep = ent_tab + (size_t)gidx * 128 + gpart * 16;
  float4 h4[4], e4[4];
#pragma unroll
  for (int j = 0; j < 4; ++j) {
    h4[j] = *(const float4*)(hp + j * 4);
    e4[j] = *(const float4*)(ep + j * 4);
  }
  // cross weights -> regionA buf1 slot (read at cross, before L2 epilogue)
  if (tid < 128) {
    int a = tid >> 5, o = (tid & 31) * 4;
    const float* s = (a == 0) ? w_cf : (a == 1) ? w_fc : (a == 2) ? w_ef : w_fe;
    *(float4*)&cw_p[a * 128 + o] = *(const float4*)(s + o);
  }

  // stage features fp32->bf16 (swizzled writes): 2048 float4, 8/thread
#pragma unroll
  for (int i = 0; i < 8; ++i) {
    int idx4 = i * 256 + tid;
    int row = idx4 >> 6, c = (idx4 & 63) * 4;
    float4 v = *(const float4*)(features + (size_t)(r0 + row) * 256 + c);
    uint2 o;
    o.x = (unsigned)f2bf(v.x) | ((unsigned)f2bf(v.y) << 16);
    o.y = (unsigned)f2bf(v.z) | ((unsigned)f2bf(v.w) << 16);
    *(uint2*)&feat_sh[row * 256 + sz(row, c)] = o;
  }

  floatx4 acc[4];
  // ---- L1: cf0 = relu(feat @ Wf + bf), K=256, N=128 ----
#pragma unroll
  for (int j = 0; j < 4; ++j) acc[j] = (floatx4){0.f, 0.f, 0.f, 0.f};
  gemm_phase<4, 256, 4, 256>(feat_sh, wfT, b_sh, acc, tid, m16, quad, wave);
#pragma unroll
  for (int mi = 0; mi < 2; ++mi)
#pragma unroll
    for (int ni = 0; ni < 2; ++ni) {
      int col = wave * 32 + ni * 16 + m16;
      float bv = bf_[col];
#pragma unroll
      for (int r = 0; r < 4; ++r) {
        int row = mi * 16 + quad * 4 + r;
        buf0[row * 128 + sz(row, col)] =
            f2bf(fmaxf(acc[mi * 2 + ni][r] + bv, 0.f));
      }
    }

  // ---- cross_compress x2 (consume gather) -> A_sh[:,128:256] ----
  // feat cols 128:256 dead (L1's final barrier drained all A reads); next
  // reader of A_sh[:,128:256] is x0, behind several barriers.
  {
    float h[16], e[16];
#pragma unroll
    for (int j = 0; j < 4; ++j) {
      h[4 * j + 0] = h4[j].x; h[4 * j + 1] = h4[j].y;
      h[4 * j + 2] = h4[j].z; h[4 * j + 3] = h4[j].w;
      e[4 * j + 0] = e4[j].x; e[4 * j + 1] = e4[j].y;
      e[4 * j + 2] = e4[j].z; e[4 * j + 3] = e4[j].w;
    }
    const float bc = b_c[0], be = b_e[0];
#pragma unroll
    for (int it = 0; it < 2; ++it) {
      float d0 = 0.f, d1 = 0.f, d2 = 0.f, d3 = 0.f;
#pragma unroll
      for (int j = 0; j < 16; ++j) {
        float wcf = cw_p[0 * 128 + gpart * 16 + j];
        float wfc = cw_p[1 * 128 + gpart * 16 + j];
        float wef = cw_p[2 * 128 + gpart * 16 + j];
        float wfe = cw_p[3 * 128 + gpart * 16 + j];
        d0 += e[j] * wcf; d1 += h[j] * wfc;
        d2 += e[j] * wef; d3 += h[j] * wfe;
      }
#pragma unroll
      for (int s = 1; s < 8; s <<= 1) {
        d0 += __shfl_xor(d0, s); d1 += __shfl_xor(d1, s);
        d2 += __shfl_xor(d2, s); d3 += __shfl_xor(d3, s);
      }
#pragma unroll
      for (int j = 0; j < 16; ++j) {
        float nh = h[j] * d0 + e[j] * d1 + bc;
        float ne = h[j] * d2 + e[j] * d3 + be;
        h[j] = nh; e[j] = ne;
      }
    }
    uint4 o0, o1;
    unsigned* w = (unsigned*)&o0;
#pragma unroll
    for (int j = 0; j < 4; ++j)
      w[j] = (unsigned)f2bf(e[2 * j]) | ((unsigned)f2bf(e[2 * j + 1]) << 16);
    w = (unsigned*)&o1;
#pragma unroll
    for (int j = 0; j < 4; ++j)
      w[j] = (unsigned)f2bf(e[8 + 2 * j]) |
             ((unsigned)f2bf(e[8 + 2 * j + 1]) << 16);
    const int c0 = 128 + gpart * 16;
    *(uint4*)&A_sh[grow * 256 + sz(grow, c0)] = o0;
    *(uint4*)&A_sh[grow * 256 + sz(grow, c0 + 8)] = o1;
  }

  // ---- L2: cf1 = relu(cf0 @ Wu + bu), K=128, N=128 ----
#pragma unroll
  for (int j = 0; j < 4; ++j) acc[j] = (floatx4){0.f, 0.f, 0.f, 0.f};
  gemm_phase<2, 128, 2, 128>(buf0, wuT, b_sh, acc, tid, m16, quad, wave);
  // L2 epilogue overwrites buf1 (cw_p dead: cross reads completed before
  // L2's first barrier in every thread's program order).
#pragma unroll
  for (int mi = 0; mi < 2; ++mi)
#pragma unroll
    for (int ni = 0; ni < 2; ++ni) {
      int col = wave * 32 + ni * 16 + m16;
      float bv = bu[col];
#pragma unroll
      for (int r = 0; r < 4; ++r) {
        int row = mi * 16 + quad * 4 + r;
        buf1[row * 128 + sz(row, col)] =
            f2bf(fmaxf(acc[mi * 2 + ni][r] + bv, 0.f));
      }
    }

  // ---- L3: cf2 = relu(cf1 @ Wu + bu) -> A_sh[:,0:128] ----
  // b_sh bufs 0,1 still hold wuT steps 0,1 from L2 (same swizzled layout).
#pragma unroll
  for (int j = 0; j < 4; ++j) acc[j] = (floatx4){0.f, 0.f, 0.f, 0.f};
  BAR_VM(0);  // buf1 (L2 epilogue ds_writes) visible to all waves
  mstep<128>(buf1, b_sh, 0, acc, m16, quad, wave);
  mstep<128>(buf1, b_sh + 8192, 64, acc, m16, quad, wave);
  BAR_VM(0);  // drain b_sh reads before x0's stage(0) overwrites b_sh
#pragma unroll
  for (int mi = 0; mi < 2; ++mi)
#pragma unroll
    for (int ni = 0; ni < 2; ++ni) {
      int col = wave * 32 + ni * 16 + m16;
      float bv = bu[col];
#pragma unroll
      for (int r = 0; r < 4; ++r) {
        int row = mi * 16 + quad * 4 + r;
        A_sh[row * 256 + sz(row, col)] =
            f2bf(fmaxf(acc[mi * 2 + ni][r] + bv, 0.f));
      }
    }

  // ---- x0 = relu(A @ W0 + b0), K=256, N=512 as 4 n-passes ----
  floatx4 acc16[16];
#pragma unroll
  for (int j = 0; j < 16; ++j) acc16[j] = (floatx4){0.f, 0.f, 0.f, 0.f};
  gemm_phase<16, 256, 4, 256>(A_sh, w0T, b_sh, acc16, tid, m16, quad, wave);
  // epilogue -> x0_sh (overwrites regionA; all A reads drained at final bar)
#pragma unroll
  for (int np = 0; np < 4; ++np)
#pragma unroll
    for (int mi = 0; mi < 2; ++mi)
#pragma unroll
      for (int ni = 0; ni < 2; ++ni) {
        int col = np * 128 + wave * 32 + ni * 16 + m16;
        float bv = b0[col];
#pragma unroll
        for (int r = 0; r < 4; ++r) {
          int row = mi * 16 + quad * 4 + r;
          x0_sh[row * 512 + sz(row, col)] =
              f2bf(fmaxf(acc16[np * 4 + mi * 2 + ni][r] + bv, 0.f));
        }
      }

  // ---- x1 = relu(x0 @ W1 + b1), K=512, N=256 as 2 n-passes ----
  // x1's stage(0) safe: x0's final barrier drained all b_sh reads; x1's
  // first barrier flushes the x0_sh epilogue ds_writes.
  floatx4 acc8[8];
#pragma unroll
  for (int j = 0; j < 8; ++j) acc8[j] = (floatx4){0.f, 0.f, 0.f, 0.f};
  gemm_phase<16, 512, 8, 512>(x0_sh, w1T, b_sh, acc8, tid, m16, quad, wave);
  // epilogue -> x1_sh aliased over b_sh (all b_sh reads drained at final bar)
#pragma unroll
  for (int np = 0; np < 2; ++np)
#pragma unroll
    for (int mi = 0; mi < 2; ++mi)
#pragma unroll
      for (int ni = 0; ni < 2; ++ni) {
        int col = np * 128 + wave * 32 + ni * 16 + m16;
        float bv = b1[col];
#pragma unroll
        for (int r = 0; r < 4; ++r)
          x1_sh[(mi * 16 + quad * 4 + r) * 264 + col] =
              f2bf(fmaxf(acc8[np * 4 + mi * 2 + ni][r] + bv, 0.f));
      }
  BAR_VM(0);

  // W2 GEMV + softmax: 8 lanes/row, 32 elems/lane. w2T direct from global
  // (4KB, L2-hot, read once per block at the tail).
  {
    int row = tid >> 3, q = tid & 7;
    float p[8];
#pragma unroll
    for (int n = 0; n < 8; ++n) p[n] = 0.f;
#pragma unroll
    for (int jb = 0; jb < 4; ++jb) {
      bf16x8 xv = *(const bf16x8*)&x1_sh[row * 264 + q * 32 + jb * 8];
#pragma unroll
      for (int n = 0; n < 8; ++n) {
        bf16x8 wv = *(const bf16x8*)(w2T + n * 256 + q * 32 + jb * 8);
#pragma unroll
        for (int j = 0; j < 8; ++j) p[n] += (float)xv[j] * (float)wv[j];
      }
    }
#pragma unroll
    for (int s = 1; s < 8; s <<= 1)
#pragma unroll
      for (int n = 0; n < 8; ++n) p[n] += __shfl_xor(p[n], s);
    if (q == 0) {
      float mx = -1e30f;
#pragma unroll
      for (int n = 0; n < 8; ++n) {
        p[n] = fmaxf(p[n] + b2[n], 0.f);
        mx = fmaxf(mx, p[n]);
      }
      float sum = 0.f;
#pragma unroll
      for (int n = 0; n < 8; ++n) { p[n] = __expf(p[n] - mx); sum += p[n]; }
      const float inv = 1.f / sum;
      const int gr = r0 + row;
      float4 o0 = {p[0] * inv, p[1] * inv, p[2] * inv, p[3] * inv};
      float4 o1 = {p[4] * inv, p[5] * inv, p[6] * inv, p[7] * inv};
      *(float4*)(out + (size_t)gr * 8) = o0;
      *(float4*)(out + (size_t)gr * 8 + 4) = o1;
      out[16384 * 8 + gr] = (float)target[gr];
    }
  }
}

extern "C" void kernel_launch(void* const* d_in, const int* in_sizes, int n_in,
                              void* d_out, int out_size, void* d_ws, size_t ws_size,
                              hipStream_t stream) {
  const float* features = (const float*)d_in[0];
  const int* ent_idx    = (const int*)d_in[1];
  const int* target     = (const int*)d_in[2];
  const float* Wf  = (const float*)d_in[3];
  const float* bf_ = (const float*)d_in[4];
  const float* Wu  = (const float*)d_in[5];
  const float* bu  = (const float*)d_in[6];
  const float* w_cf = (const float*)d_in[7];
  const float* w_fc = (const float*)d_in[8];
  const float* w_ef = (const float*)d_in[9];
  const float* w_fe = (const float*)d_in[10];
  const float* b_c  = (const float*)d_in[11];
  const float* b_e  = (const float*)d_in[12];
  const float* head_tab = (const float*)d_in[13];
  const float* ent_tab  = (const float*)d_in[14];
  const float* W0 = (const float*)d_in[15];
  const float* b0 = (const float*)d_in[16];
  const float* W1 = (const float*)d_in[17];
  const float* b1 = (const float*)d_in[18];
  const float* W2 = (const float*)d_in[19];
  const float* b2 = (const float*)d_in[20];
  float* out = (float*)d_out;

  unsigned short* ws = (unsigned short*)d_ws;
  size_t off = 0;
  auto alloc = [&](size_t n) { unsigned short* p = ws + off; off += n; return p; };
  unsigned short* wfT  = alloc(32768);
  unsigned short* wuT  = alloc(16384);
  unsigned short* w0T  = alloc(131072);
  unsigned short* w1T  = alloc(131072);
  unsigned short* w2T  = alloc(2048);
  (void)ws_size; (void)in_sizes; (void)n_in; (void)out_size;

  // K1: weight transposes only
  prep_kernel<<<305, 256, 0, stream>>>(Wf, Wu, W0, W1, W2,
                                       wfT, wuT, w0T, w1T, w2T);
  // K2: full fused per-row pipeline, counted-vmcnt triple-buffer staging
  fused_mlp_kernel<<<512, 256, 0, stream>>>(features, ent_idx, head_tab,
      ent_tab, w_cf, w_fc, w_ef, w_fe, b_c, b_e, wfT, wuT, bf_, bu,
      w0T, b0, w1T, b1, w2T, b2, target, out);
}